// Round 7
// baseline (792.673 us; speedup 1.0000x reference)
//
#include <hip/hip_runtime.h>
#include <hip/hip_bf16.h>

typedef _Float16 half8 __attribute__((ext_vector_type(8)));
typedef _Float16 half2v __attribute__((ext_vector_type(2)));
typedef float f32x4 __attribute__((ext_vector_type(4)));

#define NN 50000
#define NE 800000
#define NBN 16            // receivers owned per tp block
#define NTPB (NN / NBN)   // 3125 tp blocks (exact)

__device__ __forceinline__ float swishf(float v) { return v / (1.f + __expf(-v)); }

// ---------------------------------------------------------------------------
// Pack W3 [64][256] and W2 [64][64] into MFMA-B fragment order (f16).
// w3p[t*8+u] = W3[j>>2][4*f+(j&3)],  j=32ks+8(lane>>4)+u, f=16nt+(lane&15)
// w2p[t*8+u] = W2[32kk+8(lane>>4)+u][16nt+(lane&15)]
// ---------------------------------------------------------------------------
__global__ void pack_kernel(const float* __restrict__ W3, const float* __restrict__ W2,
                            _Float16* __restrict__ w3p, _Float16* __restrict__ w2p) {
  const int b = blockIdx.x, tid = threadIdx.x;
  if (b < 8) {
    int t = b * 256 + tid;
    int lane = t & 63, nt = (t >> 6) & 3, ks = t >> 8;
    int f = 16 * nt + (lane & 15);
    int jb = 32 * ks + 8 * (lane >> 4);
#pragma unroll
    for (int u = 0; u < 8; ++u) {
      int j = jb + u;
      w3p[t * 8 + u] = (_Float16)W3[(j >> 2) * 256 + 4 * f + (j & 3)];
    }
  } else {
    int t = (b - 8) * 256 + tid;
    if (t < 512) {
      int lane = t & 63, nt = (t >> 6) & 3, kk = t >> 8;
      int c = 16 * nt + (lane & 15);
      int kb = 32 * kk + 8 * (lane >> 4);
#pragma unroll
      for (int u = 0; u < 8; ++u)
        w2p[t * 8 + u] = (_Float16)W2[(kb + u) * 64 + c];
    }
  }
}

// ---------------------------------------------------------------------------
// linear_up: Y[row] = X[row] @ W  (f16 out)
// ---------------------------------------------------------------------------
__global__ __launch_bounds__(256)
void linear_up_kernel(const float* __restrict__ X, const float* __restrict__ W,
                      _Float16* __restrict__ Y) {
  int gid = blockIdx.x * 256 + (int)threadIdx.x;
  int row = gid >> 6;
  int lane = threadIdx.x & 63;
  const float* xr = X + (long)row * 64;
  float acc = 0.f;
#pragma unroll
  for (int k = 0; k < 64; ++k) acc = fmaf(xr[k], W[k * 64 + lane], acc);
  Y[(long)row * 64 + lane] = (_Float16)acc;
}

// ---------------------------------------------------------------------------
// CSR build: hist (+ pack sender|mask), 3-phase coalesced scan, scatter
// ---------------------------------------------------------------------------
__global__ void hist_pack_kernel(const int* __restrict__ rcv, const int* __restrict__ snd,
                                 const int* __restrict__ msk, int* __restrict__ deg,
                                 int* __restrict__ sm) {
  int e = blockIdx.x * 256 + threadIdx.x;
  if (e < NE) {
    atomicAdd(&deg[rcv[e]], 1);
    sm[e] = (snd[e] & 0xFFFF) | (msk[e] ? (1 << 16) : 0);
  }
}

__global__ __launch_bounds__(256)
void scan1_kernel(const int* __restrict__ deg, int* __restrict__ bsum) {
  __shared__ int s[256];
  int gid = blockIdx.x * 256 + threadIdx.x;
  s[threadIdx.x] = (gid < NN) ? deg[gid] : 0;
  __syncthreads();
  for (int d = 128; d > 0; d >>= 1) {
    if (threadIdx.x < d) s[threadIdx.x] += s[threadIdx.x + d];
    __syncthreads();
  }
  if (threadIdx.x == 0) bsum[blockIdx.x] = s[0];
}

__global__ __launch_bounds__(256)
void scan2_kernel(const int* __restrict__ bsum, int* __restrict__ boff) {
  __shared__ int s[256];
  int t = threadIdx.x;
  int v = (t < 196) ? bsum[t] : 0;
  s[t] = v;
  __syncthreads();
  for (int d = 1; d < 256; d <<= 1) {
    int x = (t >= d) ? s[t - d] : 0;
    __syncthreads();
    s[t] += x;
    __syncthreads();
  }
  boff[t] = s[t] - v;   // exclusive
}

__global__ __launch_bounds__(256)
void scan3_kernel(const int* __restrict__ deg, const int* __restrict__ boff,
                  int* __restrict__ pos, int* __restrict__ cur) {
  __shared__ int s[256];
  int t = threadIdx.x, gid = blockIdx.x * 256 + t;
  int v = (gid < NN) ? deg[gid] : 0;
  s[t] = v;
  __syncthreads();
  for (int d = 1; d < 256; d <<= 1) {
    int x = (t >= d) ? s[t - d] : 0;
    __syncthreads();
    s[t] += x;
    __syncthreads();
  }
  int ex = s[t] - v + boff[blockIdx.x];
  if (gid < NN) {
    pos[gid] = ex;
    cur[gid] = ex;
    if (gid == NN - 1) pos[NN] = ex + v;
  }
}

__global__ void scatter_kernel(const int* __restrict__ rcv, int* __restrict__ cur,
                               int* __restrict__ eidx) {
  int e = blockIdx.x * 256 + threadIdx.x;
  if (e < NE) {
    int slot = atomicAdd(&cur[rcv[e]], 1);
    eidx[slot] = e;
  }
}

// ---------------------------------------------------------------------------
// Radial MLP, streaming (unchanged from round 6): h2p rows in permuted layout
// pos(ch) = 16*((ch>>1)&3) + 2*(ch>>3) + (ch&1), absolute edge indexing.
// ---------------------------------------------------------------------------
__global__ __launch_bounds__(256, 4)
void radial_kernel(const float* __restrict__ rad, const float* __restrict__ W1,
                   const _Float16* __restrict__ w2p, _Float16* __restrict__ h2p) {
  __shared__ float    s_r[64][9];
  __shared__ _Float16 s_h1[64][72];
  __shared__ _Float16 s_hp[64][72];

  const int t = threadIdx.x;
  const long e0 = (long)blockIdx.x * 64;

  for (int i = t; i < 512; i += 256) s_r[i >> 3][i & 7] = rad[e0 * 8 + i];
  __syncthreads();

  {
    const int e = t & 63, c0 = (t >> 6) * 16;
    float rv[8];
#pragma unroll
    for (int k = 0; k < 8; ++k) rv[k] = s_r[e][k];
#pragma unroll
    for (int p = 0; p < 8; ++p) {
      float a0 = 0.f, a1 = 0.f;
#pragma unroll
      for (int k = 0; k < 8; ++k) {
        a0 = fmaf(rv[k], W1[k * 64 + c0 + 2 * p], a0);
        a1 = fmaf(rv[k], W1[k * 64 + c0 + 2 * p + 1], a1);
      }
      half2v h = { (_Float16)swishf(a0), (_Float16)swishf(a1) };
      *reinterpret_cast<half2v*>(&s_h1[e][c0 + 2 * p]) = h;
    }
  }
  __syncthreads();

  {
    const int w = t >> 6, lane = t & 63, m = lane & 15, g = lane >> 4;
    f32x4 acc[4];
#pragma unroll
    for (int nt = 0; nt < 4; ++nt) acc[nt] = (f32x4){0.f, 0.f, 0.f, 0.f};
#pragma unroll
    for (int kk = 0; kk < 2; ++kk) {
      half8 a = *reinterpret_cast<const half8*>(&s_h1[w * 16 + m][32 * kk + 8 * g]);
#pragma unroll
      for (int nt = 0; nt < 4; ++nt) {
        half8 bfr = *reinterpret_cast<const half8*>(w2p + ((size_t)(kk * 4 + nt) * 64 + lane) * 8);
        acc[nt] = __builtin_amdgcn_mfma_f32_16x16x32_f16(a, bfr, acc[nt], 0, 0, 0);
      }
    }
    const int col = lane & 15, rg = lane >> 4;
    const int pbase = 16 * ((col >> 1) & 3) + 2 * (col >> 3) + (col & 1);
#pragma unroll
    for (int nt = 0; nt < 4; ++nt) {
      const int pos = pbase + 4 * nt;
#pragma unroll
      for (int i = 0; i < 4; ++i) {
        const int erow = w * 16 + rg * 4 + i;
        s_hp[erow][pos] = (_Float16)swishf(acc[nt][i]);
      }
    }
  }
  __syncthreads();

  {
    const int row = t >> 2, seg = t & 3;
    uint4 v0 = *reinterpret_cast<const uint4*>(&s_hp[row][seg * 16]);
    uint4 v1 = *reinterpret_cast<const uint4*>(&s_hp[row][seg * 16 + 8]);
    _Float16* dst = h2p + ((long)blockIdx.x * 64 + row) * 64 + seg * 16;
    *reinterpret_cast<uint4*>(dst) = v0;
    *reinterpret_cast<uint4*>(dst + 8) = v1;
  }
}

// ---------------------------------------------------------------------------
// tp_gather: block b owns receivers [16b, 16b+16). Loops CSR edges in 64-edge
// MFMA tiles; msg accumulated into LDS agg tile (ds atomics, disjoint across
// blocks -> NO global atomics). Fused linear_down epilogue writes d_out.
// ---------------------------------------------------------------------------
__global__ __launch_bounds__(256, 6)
void tp_gather_kernel(const _Float16* __restrict__ xup, const float* __restrict__ ef,
                      const _Float16* __restrict__ h2p, const int* __restrict__ sm,
                      const int* __restrict__ eidx, const int* __restrict__ pos,
                      const _Float16* __restrict__ w3p, const float* __restrict__ W_dn,
                      float* __restrict__ out) {
  __shared__ float    s_ef[64][4];
  __shared__ _Float16 s_xs[64][72];
  __shared__ float    s_agg[NBN][65];
  __shared__ int      s_posL[NBN + 1];
  __shared__ unsigned char s_rloc[64];

  const int t = threadIdx.x;
  const int node0 = blockIdx.x * NBN;

  if (t < NBN + 1) s_posL[t] = pos[node0 + t];
  for (int i = t; i < NBN * 65; i += 256) (&s_agg[0][0])[i] = 0.f;
  __syncthreads();

  const int pos0 = s_posL[0], pos1 = s_posL[NBN];
  const int w = t >> 6, lane = t & 63, m = lane & 15, g = lane >> 4;
  const int col = lane & 15, rg = lane >> 4;

  for (int t0 = pos0; t0 < pos1; t0 += 64) {
    // ---- stage: 4 threads per edge row ----
    {
      const int e = t >> 2, q = t & 3;
      const int a = t0 + e;
      const bool valid = a < pos1;
      const int eid = eidx[valid ? a : (pos1 - 1)];
      s_ef[e][q] = ef[(long)eid * 4 + q];
      const int smv = sm[eid];
      const bool mk = valid && (smv >> 16);
      const int sn = smv & 0xFFFF;
      uint4 v0 = {0, 0, 0, 0}, v1 = {0, 0, 0, 0};
      if (mk) {
        const uint4* src = reinterpret_cast<const uint4*>(xup + (long)sn * 64 + q * 16);
        v0 = src[0]; v1 = src[1];
      }
      *reinterpret_cast<uint4*>(&s_xs[e][q * 16]) = v0;
      *reinterpret_cast<uint4*>(&s_xs[e][q * 16 + 8]) = v1;
    }
    if (t < 64) {
      const int a = t0 + t;
      int k = 0;
#pragma unroll
      for (int j = 1; j < NBN; ++j) k += (a >= s_posL[j]);
      s_rloc[t] = (unsigned char)k;   // invalid rows -> 15, but xs=0 so add 0
    }
    __syncthreads();

    // ---- MFMA: per-lane h2 frags gathered from h2p ----
    const int e_m = w * 16 + m;
    const int am = t0 + e_m;
    const int eidm = eidx[am < pos1 ? am : (pos1 - 1)];
    const _Float16* hrow = h2p + (long)eidm * 64 + g * 16;
    half8 hlo = *reinterpret_cast<const half8*>(hrow);
    half8 hhi = *reinterpret_cast<const half8*>(hrow + 8);

    float ef4[4];
#pragma unroll
    for (int l = 0; l < 4; ++l) ef4[l] = s_ef[e_m][l];

    f32x4 acc[4];
#pragma unroll
    for (int nt = 0; nt < 4; ++nt) acc[nt] = (f32x4){0.f, 0.f, 0.f, 0.f};

#pragma unroll
    for (int ks = 0; ks < 8; ++ks) {
      const float h0  = (float)(ks < 4 ? hlo[2 * ks]     : hhi[2 * (ks - 4)]);
      const float h1v = (float)(ks < 4 ? hlo[2 * ks + 1] : hhi[2 * (ks - 4) + 1]);
      half8 a;
#pragma unroll
      for (int l = 0; l < 4; ++l) {
        a[l]     = (_Float16)(h0 * ef4[l]);
        a[4 + l] = (_Float16)(h1v * ef4[l]);
      }
#pragma unroll
      for (int nt = 0; nt < 4; ++nt) {
        half8 bfr = *reinterpret_cast<const half8*>(w3p + ((size_t)(ks * 4 + nt) * 64 + lane) * 8);
        acc[nt] = __builtin_amdgcn_mfma_f32_16x16x32_f16(a, bfr, acc[nt], 0, 0, 0);
      }
    }

    // ---- epilogue: multiply x_s, ds-atomic into LDS agg tile ----
#pragma unroll
    for (int nt = 0; nt < 4; ++nt) {
      const int f = nt * 16 + col;
#pragma unroll
      for (int i = 0; i < 4; ++i) {
        const int e_row = w * 16 + rg * 4 + i;
        const float v = acc[nt][i] * (float)s_xs[e_row][f];
        atomicAdd(&s_agg[s_rloc[e_row]][f], v);
      }
    }
    __syncthreads();
  }

  // ---- fused linear_down: out[node0+r] = (s_agg[r]/16) @ W_dn ----
  {
    const int r = t >> 4, c0 = (t & 15) * 4;
    float a0 = 0.f, a1 = 0.f, a2 = 0.f, a3 = 0.f;
    for (int k = 0; k < 64; ++k) {
      const float x = s_agg[r][k];
      const float4 wv = *reinterpret_cast<const float4*>(W_dn + k * 64 + c0);
      a0 = fmaf(x, wv.x, a0);
      a1 = fmaf(x, wv.y, a1);
      a2 = fmaf(x, wv.z, a2);
      a3 = fmaf(x, wv.w, a3);
    }
    float4 o = { a0 * 0.0625f, a1 * 0.0625f, a2 * 0.0625f, a3 * 0.0625f };
    *reinterpret_cast<float4*>(out + (long)(node0 + r) * 64 + c0) = o;
  }
}

extern "C" void kernel_launch(void* const* d_in, const int* in_sizes, int n_in,
                              void* d_out, int out_size, void* d_ws, size_t ws_size,
                              hipStream_t stream) {
  const float* nf   = (const float*)d_in[0];
  const float* ef   = (const float*)d_in[1];
  const float* rad  = (const float*)d_in[2];
  const int*   snd  = (const int*)d_in[3];
  const int*   rcv  = (const int*)d_in[4];
  const int*   msk  = (const int*)d_in[5];
  const float* W_up = (const float*)d_in[6];
  const float* W1   = (const float*)d_in[7];
  const float* W2   = (const float*)d_in[8];
  const float* W3   = (const float*)d_in[9];
  const float* W_dn = (const float*)d_in[10];
  float* out = (float*)d_out;

  // workspace layout (~115.8 MB; round 6 proved >= ~121.6 MB available)
  _Float16* h2p  = (_Float16*)d_ws;                 // 800000*64 f16 = 102.4 MB
  _Float16* xbuf = h2p + (size_t)NE * 64;           // 6.4 MB
  _Float16* w3p  = xbuf + (size_t)NN * 64;          // 32 KB
  _Float16* w2p  = w3p + 2048 * 8;                  // 8 KB
  int*      sm   = (int*)(w2p + 512 * 8);           // 3.2 MB
  int*      eidx = sm + NE;                         // 3.2 MB
  int*      deg  = eidx + NE;                       // 200 KB
  int*      pos  = deg + NN;                        // 200 KB (+1)
  int*      cur  = pos + NN + 1;                    // 200 KB
  int*      bsum = cur + NN;                        // 1 KB
  int*      boff = bsum + 256;                      // 1 KB

  hipMemsetAsync(deg, 0, (size_t)NN * sizeof(int), stream);

  hist_pack_kernel<<<NE / 256, 256, 0, stream>>>(rcv, snd, msk, deg, sm);
  scan1_kernel<<<196, 256, 0, stream>>>(deg, bsum);
  scan2_kernel<<<1, 256, 0, stream>>>(bsum, boff);
  scan3_kernel<<<196, 256, 0, stream>>>(deg, boff, pos, cur);
  scatter_kernel<<<NE / 256, 256, 0, stream>>>(rcv, cur, eidx);

  pack_kernel<<<10, 256, 0, stream>>>(W3, W2, w3p, w2p);
  linear_up_kernel<<<(NN * 64) / 256, 256, 0, stream>>>(nf, W_up, xbuf);
  radial_kernel<<<NE / 64, 256, 0, stream>>>(rad, W1, w2p, h2p);

  tp_gather_kernel<<<NTPB, 256, 0, stream>>>(xbuf, ef, h2p, sm, eidx, pos,
                                             w3p, W_dn, out);
}

// Round 8
// 332.383 us; speedup vs baseline: 2.3848x; 2.3848x over previous
//
#include <hip/hip_runtime.h>
#include <hip/hip_bf16.h>

typedef _Float16 half8 __attribute__((ext_vector_type(8)));
typedef _Float16 half4v __attribute__((ext_vector_type(4)));
typedef _Float16 half2v __attribute__((ext_vector_type(2)));
typedef float f32x4 __attribute__((ext_vector_type(4)));

#define NN 50000
#define NE 800000

__device__ __forceinline__ float swishf(float v) { return v / (1.f + __expf(-v)); }

// ---------------------------------------------------------------------------
// Pack W3 [64][256] and W2 [64][64] into MFMA-B fragment order (f16).
// w3p[t*8+u] = W3[j>>2][4*f+(j&3)],  j=32ks+8(lane>>4)+u, f=16nt+(lane&15)
// w2p[t*8+u] = W2[32kk+8(lane>>4)+u][16nt+(lane&15)]
// ---------------------------------------------------------------------------
__global__ void pack_kernel(const float* __restrict__ W3, const float* __restrict__ W2,
                            _Float16* __restrict__ w3p, _Float16* __restrict__ w2p) {
  const int b = blockIdx.x, tid = threadIdx.x;
  if (b < 8) {
    int t = b * 256 + tid;
    int lane = t & 63, nt = (t >> 6) & 3, ks = t >> 8;
    int f = 16 * nt + (lane & 15);
    int jb = 32 * ks + 8 * (lane >> 4);
#pragma unroll
    for (int u = 0; u < 8; ++u) {
      int j = jb + u;
      w3p[t * 8 + u] = (_Float16)W3[(j >> 2) * 256 + 4 * f + (j & 3)];
    }
  } else {
    int t = (b - 8) * 256 + tid;
    if (t < 512) {
      int lane = t & 63, nt = (t >> 6) & 3, kk = t >> 8;
      int c = 16 * nt + (lane & 15);
      int kb = 32 * kk + 8 * (lane >> 4);
#pragma unroll
      for (int u = 0; u < 8; ++u)
        w2p[t * 8 + u] = (_Float16)W2[(kb + u) * 64 + c];
    }
  }
}

// ---------------------------------------------------------------------------
// linear_up: Y[row] = X[row] @ W  (f16 out)
// ---------------------------------------------------------------------------
__global__ __launch_bounds__(256)
void linear_up_kernel(const float* __restrict__ X, const float* __restrict__ W,
                      _Float16* __restrict__ Y) {
  int gid = blockIdx.x * 256 + (int)threadIdx.x;
  int row = gid >> 6;
  int lane = threadIdx.x & 63;
  const float* xr = X + (long)row * 64;
  float acc = 0.f;
#pragma unroll
  for (int k = 0; k < 64; ++k) acc = fmaf(xr[k], W[k * 64 + lane], acc);
  Y[(long)row * 64 + lane] = (_Float16)acc;
}

// ---------------------------------------------------------------------------
// CSR build: hist, 3-phase coalesced scan, scatter  (receiver -> edge list)
// ---------------------------------------------------------------------------
__global__ void hist_kernel(const int* __restrict__ rcv, int* __restrict__ deg) {
  int e = blockIdx.x * 256 + threadIdx.x;
  if (e < NE) atomicAdd(&deg[rcv[e]], 1);
}

__global__ __launch_bounds__(256)
void scan1_kernel(const int* __restrict__ deg, int* __restrict__ bsum) {
  __shared__ int s[256];
  int gid = blockIdx.x * 256 + threadIdx.x;
  s[threadIdx.x] = (gid < NN) ? deg[gid] : 0;
  __syncthreads();
  for (int d = 128; d > 0; d >>= 1) {
    if (threadIdx.x < d) s[threadIdx.x] += s[threadIdx.x + d];
    __syncthreads();
  }
  if (threadIdx.x == 0) bsum[blockIdx.x] = s[0];
}

__global__ __launch_bounds__(256)
void scan2_kernel(const int* __restrict__ bsum, int* __restrict__ boff) {
  __shared__ int s[256];
  int t = threadIdx.x;
  int v = (t < 196) ? bsum[t] : 0;
  s[t] = v;
  __syncthreads();
  for (int d = 1; d < 256; d <<= 1) {
    int x = (t >= d) ? s[t - d] : 0;
    __syncthreads();
    s[t] += x;
    __syncthreads();
  }
  boff[t] = s[t] - v;   // exclusive
}

__global__ __launch_bounds__(256)
void scan3_kernel(const int* __restrict__ deg, const int* __restrict__ boff,
                  int* __restrict__ pos, int* __restrict__ cur) {
  __shared__ int s[256];
  int t = threadIdx.x, gid = blockIdx.x * 256 + t;
  int v = (gid < NN) ? deg[gid] : 0;
  s[t] = v;
  __syncthreads();
  for (int d = 1; d < 256; d <<= 1) {
    int x = (t >= d) ? s[t - d] : 0;
    __syncthreads();
    s[t] += x;
    __syncthreads();
  }
  int ex = s[t] - v + boff[blockIdx.x];
  if (gid < NN) {
    pos[gid] = ex;
    cur[gid] = ex;
    if (gid == NN - 1) pos[NN] = ex + v;
  }
}

__global__ void scatter_kernel(const int* __restrict__ rcv, int* __restrict__ cur,
                               int* __restrict__ eidx) {
  int e = blockIdx.x * 256 + threadIdx.x;
  if (e < NE) {
    int slot = atomicAdd(&cur[rcv[e]], 1);
    eidx[slot] = e;
  }
}

// ---------------------------------------------------------------------------
// fused_tp: per 64-edge tile (natural edge order, all streaming):
//   stage r/ef/x_s -> h1 = swish(r@W1) (VALU) -> h2 = swish(h1@W2) (MFMA,
//   via LDS s_hp in permuted layout pos(ch)=16*((ch>>1)&3)+2*(ch>>3)+(ch&1))
//   -> msg = (A' @ W3re) * x_s (MFMA) -> coalesced f16 msg[e] store.
// No atomics, no global h2 round-trip.
// ---------------------------------------------------------------------------
__global__ __launch_bounds__(256, 4)
void fused_tp_kernel(const float* __restrict__ rad, const float* __restrict__ ef,
                     const _Float16* __restrict__ xup, const int* __restrict__ snd,
                     const int* __restrict__ msk, const float* __restrict__ W1,
                     const _Float16* __restrict__ w2p, const _Float16* __restrict__ w3p,
                     _Float16* __restrict__ msg) {
  __shared__ float    s_r[64][9];
  __shared__ float    s_ef[64][4];
  __shared__ _Float16 s_xs[64][72];
  __shared__ _Float16 s_h1[64][72];
  __shared__ _Float16 s_hp[64][72];

  const int t = threadIdx.x;
  const long e0 = (long)blockIdx.x * 64;
  const int w = t >> 6, lane = t & 63, m = lane & 15, g = lane >> 4;

  // ---- stage: rad / ef sequential, x_s gather (4 threads per edge) ----
  for (int i = t; i < 512; i += 256) s_r[i >> 3][i & 7] = rad[e0 * 8 + i];
  s_ef[t >> 2][t & 3] = ef[e0 * 4 + t];
  {
    const int e = t >> 2, q = t & 3;
    const int sn = snd[e0 + e];
    const int mk = msk[e0 + e];
    uint4 v0 = {0, 0, 0, 0}, v1 = {0, 0, 0, 0};
    if (mk) {
      const uint4* src = reinterpret_cast<const uint4*>(xup + (long)sn * 64 + q * 16);
      v0 = src[0]; v1 = src[1];
    }
    *reinterpret_cast<uint4*>(&s_xs[e][q * 16]) = v0;
    *reinterpret_cast<uint4*>(&s_xs[e][q * 16 + 8]) = v1;
  }
  __syncthreads();

  // ---- h1 = swish(r @ W1): thread (e, 16 channels), W1 wave-uniform ----
  {
    const int e = t & 63, c0 = (t >> 6) * 16;
    float rv[8];
#pragma unroll
    for (int k = 0; k < 8; ++k) rv[k] = s_r[e][k];
#pragma unroll
    for (int p = 0; p < 8; ++p) {
      float a0 = 0.f, a1 = 0.f;
#pragma unroll
      for (int k = 0; k < 8; ++k) {
        a0 = fmaf(rv[k], W1[k * 64 + c0 + 2 * p], a0);
        a1 = fmaf(rv[k], W1[k * 64 + c0 + 2 * p + 1], a1);
      }
      half2v h = { (_Float16)swishf(a0), (_Float16)swishf(a1) };
      *reinterpret_cast<half2v*>(&s_h1[e][c0 + 2 * p]) = h;
    }
  }
  __syncthreads();

  // ---- h2 = swish(h1 @ W2) via MFMA -> s_hp (permuted channel layout) ----
  {
    f32x4 acc[4];
#pragma unroll
    for (int nt = 0; nt < 4; ++nt) acc[nt] = (f32x4){0.f, 0.f, 0.f, 0.f};
#pragma unroll
    for (int kk = 0; kk < 2; ++kk) {
      half8 a = *reinterpret_cast<const half8*>(&s_h1[w * 16 + m][32 * kk + 8 * g]);
#pragma unroll
      for (int nt = 0; nt < 4; ++nt) {
        half8 bfr = *reinterpret_cast<const half8*>(w2p + ((size_t)(kk * 4 + nt) * 64 + lane) * 8);
        acc[nt] = __builtin_amdgcn_mfma_f32_16x16x32_f16(a, bfr, acc[nt], 0, 0, 0);
      }
    }
    const int col = lane & 15, rg = lane >> 4;
    const int pbase = 16 * ((col >> 1) & 3) + 2 * (col >> 3) + (col & 1);
#pragma unroll
    for (int nt = 0; nt < 4; ++nt) {
      const int pos = pbase + 4 * nt;
#pragma unroll
      for (int i = 0; i < 4; ++i) {
        const int erow = w * 16 + rg * 4 + i;
        s_hp[erow][pos] = (_Float16)swishf(acc[nt][i]);
      }
    }
  }
  __syncthreads();

  // ---- TP: msg = (A' @ W3re) * x_s, coalesced f16 store in edge order ----
  {
    const int e_m = w * 16 + m;
    const _Float16* hrow = &s_hp[e_m][g * 16];
    half8 hlo = *reinterpret_cast<const half8*>(hrow);
    half8 hhi = *reinterpret_cast<const half8*>(hrow + 8);

    float ef4[4];
#pragma unroll
    for (int l = 0; l < 4; ++l) ef4[l] = s_ef[e_m][l];

    f32x4 acc[4];
#pragma unroll
    for (int nt = 0; nt < 4; ++nt) acc[nt] = (f32x4){0.f, 0.f, 0.f, 0.f};

#pragma unroll
    for (int ks = 0; ks < 8; ++ks) {
      const float h0  = (float)(ks < 4 ? hlo[2 * ks]     : hhi[2 * (ks - 4)]);
      const float h1v = (float)(ks < 4 ? hlo[2 * ks + 1] : hhi[2 * (ks - 4) + 1]);
      half8 a;
#pragma unroll
      for (int l = 0; l < 4; ++l) {
        a[l]     = (_Float16)(h0 * ef4[l]);
        a[4 + l] = (_Float16)(h1v * ef4[l]);
      }
#pragma unroll
      for (int nt = 0; nt < 4; ++nt) {
        half8 bfr = *reinterpret_cast<const half8*>(w3p + ((size_t)(ks * 4 + nt) * 64 + lane) * 8);
        acc[nt] = __builtin_amdgcn_mfma_f32_16x16x32_f16(a, bfr, acc[nt], 0, 0, 0);
      }
    }

    const int col = lane & 15, rg = lane >> 4;
#pragma unroll
    for (int nt = 0; nt < 4; ++nt) {
      const int f = nt * 16 + col;
#pragma unroll
      for (int i = 0; i < 4; ++i) {
        const int e_row = w * 16 + rg * 4 + i;
        msg[(e0 + e_row) * 64 + f] = (_Float16)(acc[nt][i] * (float)s_xs[e_row][f]);
      }
    }
  }
}

// ---------------------------------------------------------------------------
// gather_down: block owns 16 nodes; 16 threads per node sum its CSR msg rows
// (one exact 128B line per row), then fused /16 @ W_down epilogue -> out.
// No atomics anywhere.
// ---------------------------------------------------------------------------
__global__ __launch_bounds__(256, 8)
void gather_down_kernel(const _Float16* __restrict__ msg, const int* __restrict__ eidx,
                        const int* __restrict__ pos, const float* __restrict__ W_dn,
                        float* __restrict__ out) {
  __shared__ int   s_pos[17];
  __shared__ int   s_eidx[512];
  __shared__ float s_agg[16][65];

  const int t = threadIdx.x;
  const int node0 = blockIdx.x * 16;

  if (t < 17) s_pos[t] = pos[node0 + t];
  __syncthreads();
  const int p0 = s_pos[0], p1 = s_pos[16];
  for (int i = t; i < p1 - p0; i += 256) s_eidx[i] = eidx[p0 + i];
  __syncthreads();

  const int tg = t >> 4, tl = t & 15;
  float a0 = 0.f, a1 = 0.f, a2 = 0.f, a3 = 0.f;
  for (int a = s_pos[tg]; a < s_pos[tg + 1]; ++a) {
    const int eid = s_eidx[a - p0];
    half4v v = *reinterpret_cast<const half4v*>(msg + (long)eid * 64 + tl * 4);
    a0 += (float)v[0]; a1 += (float)v[1]; a2 += (float)v[2]; a3 += (float)v[3];
  }
  s_agg[tg][tl * 4 + 0] = a0;
  s_agg[tg][tl * 4 + 1] = a1;
  s_agg[tg][tl * 4 + 2] = a2;
  s_agg[tg][tl * 4 + 3] = a3;
  __syncthreads();

  // fused linear_down: out[node0+r] = (s_agg[r]/16) @ W_dn
  {
    const int r = t >> 4, c0 = (t & 15) * 4;
    float b0 = 0.f, b1 = 0.f, b2 = 0.f, b3 = 0.f;
    for (int k = 0; k < 64; ++k) {
      const float x = s_agg[r][k];
      const float4 wv = *reinterpret_cast<const float4*>(W_dn + k * 64 + c0);
      b0 = fmaf(x, wv.x, b0);
      b1 = fmaf(x, wv.y, b1);
      b2 = fmaf(x, wv.z, b2);
      b3 = fmaf(x, wv.w, b3);
    }
    float4 o = { b0 * 0.0625f, b1 * 0.0625f, b2 * 0.0625f, b3 * 0.0625f };
    *reinterpret_cast<float4*>(out + (long)(node0 + r) * 64 + c0) = o;
  }
}

extern "C" void kernel_launch(void* const* d_in, const int* in_sizes, int n_in,
                              void* d_out, int out_size, void* d_ws, size_t ws_size,
                              hipStream_t stream) {
  const float* nf   = (const float*)d_in[0];
  const float* ef   = (const float*)d_in[1];
  const float* rad  = (const float*)d_in[2];
  const int*   snd  = (const int*)d_in[3];
  const int*   rcv  = (const int*)d_in[4];
  const int*   msk  = (const int*)d_in[5];
  const float* W_up = (const float*)d_in[6];
  const float* W1   = (const float*)d_in[7];
  const float* W2   = (const float*)d_in[8];
  const float* W3   = (const float*)d_in[9];
  const float* W_dn = (const float*)d_in[10];
  float* out = (float*)d_out;

  // workspace layout (~112.7 MB; round 7 proved >= ~115.8 MB available)
  _Float16* msg  = (_Float16*)d_ws;                 // 800000*64 f16 = 102.4 MB
  _Float16* xbuf = msg + (size_t)NE * 64;           // 6.4 MB
  _Float16* w3p  = xbuf + (size_t)NN * 64;          // 32 KB
  _Float16* w2p  = w3p + 2048 * 8;                  // 8 KB
  int*      eidx = (int*)(w2p + 512 * 8);           // 3.2 MB
  int*      deg  = eidx + NE;                       // 200 KB
  int*      pos  = deg + NN;                        // 200 KB (+1)
  int*      cur  = pos + NN + 1;                    // 200 KB
  int*      bsum = cur + NN;                        // 1 KB
  int*      boff = bsum + 256;                      // 1 KB

  hipMemsetAsync(deg, 0, (size_t)NN * sizeof(int), stream);

  hist_kernel<<<NE / 256, 256, 0, stream>>>(rcv, deg);
  scan1_kernel<<<196, 256, 0, stream>>>(deg, bsum);
  scan2_kernel<<<1, 256, 0, stream>>>(bsum, boff);
  scan3_kernel<<<196, 256, 0, stream>>>(deg, boff, pos, cur);
  scatter_kernel<<<NE / 256, 256, 0, stream>>>(rcv, cur, eidx);

  pack_kernel<<<10, 256, 0, stream>>>(W3, W2, w3p, w2p);
  linear_up_kernel<<<(NN * 64) / 256, 256, 0, stream>>>(nf, W_up, xbuf);

  fused_tp_kernel<<<NE / 64, 256, 0, stream>>>(rad, ef, xbuf, snd, msk,
                                               W1, w2p, w3p, msg);

  gather_down_kernel<<<NN / 16, 256, 0, stream>>>(msg, eidx, pos, W_dn, out);
}

// Round 9
// 286.479 us; speedup vs baseline: 2.7669x; 1.1602x over previous
//
#include <hip/hip_runtime.h>
#include <hip/hip_bf16.h>

typedef _Float16 half8 __attribute__((ext_vector_type(8)));
typedef _Float16 half4v __attribute__((ext_vector_type(4)));
typedef _Float16 half2v __attribute__((ext_vector_type(2)));
typedef float f32x4 __attribute__((ext_vector_type(4)));

#define NN 50000
#define NE 800000

// fast swish: v * rcp(1+exp(-v)) -- avoids the ~10-inst exact f32 divide
__device__ __forceinline__ float swishf(float v) {
  return v * __builtin_amdgcn_rcpf(1.f + __expf(-v));
}

// ---------------------------------------------------------------------------
// Pack W3 [64][256] and W2 [64][64] into MFMA-B fragment order (f16).
// w3p[t*8+u] = W3[j>>2][4*f+(j&3)],  j=32ks+8(lane>>4)+u, f=16nt+(lane&15)
// w2p[t*8+u] = W2[32kk+8(lane>>4)+u][16nt+(lane&15)]
// ---------------------------------------------------------------------------
__global__ void pack_kernel(const float* __restrict__ W3, const float* __restrict__ W2,
                            _Float16* __restrict__ w3p, _Float16* __restrict__ w2p) {
  const int b = blockIdx.x, tid = threadIdx.x;
  if (b < 8) {
    int t = b * 256 + tid;
    int lane = t & 63, nt = (t >> 6) & 3, ks = t >> 8;
    int f = 16 * nt + (lane & 15);
    int jb = 32 * ks + 8 * (lane >> 4);
#pragma unroll
    for (int u = 0; u < 8; ++u) {
      int j = jb + u;
      w3p[t * 8 + u] = (_Float16)W3[(j >> 2) * 256 + 4 * f + (j & 3)];
    }
  } else {
    int t = (b - 8) * 256 + tid;
    if (t < 512) {
      int lane = t & 63, nt = (t >> 6) & 3, kk = t >> 8;
      int c = 16 * nt + (lane & 15);
      int kb = 32 * kk + 8 * (lane >> 4);
#pragma unroll
      for (int u = 0; u < 8; ++u)
        w2p[t * 8 + u] = (_Float16)W2[(kb + u) * 64 + c];
    }
  }
}

// ---------------------------------------------------------------------------
// linear_up: Y[row] = X[row] @ W  (f16 out)
// ---------------------------------------------------------------------------
__global__ __launch_bounds__(256)
void linear_up_kernel(const float* __restrict__ X, const float* __restrict__ W,
                      _Float16* __restrict__ Y) {
  int gid = blockIdx.x * 256 + (int)threadIdx.x;
  int row = gid >> 6;
  int lane = threadIdx.x & 63;
  const float* xr = X + (long)row * 64;
  float acc = 0.f;
#pragma unroll
  for (int k = 0; k < 64; ++k) acc = fmaf(xr[k], W[k * 64 + lane], acc);
  Y[(long)row * 64 + lane] = (_Float16)acc;
}

// ---------------------------------------------------------------------------
// CSR offsets: hist, 3-phase coalesced scan (pos = exclusive prefix; cur copy)
// ---------------------------------------------------------------------------
__global__ void hist_kernel(const int* __restrict__ rcv, int* __restrict__ deg) {
  int e = blockIdx.x * 256 + threadIdx.x;
  if (e < NE) atomicAdd(&deg[rcv[e]], 1);
}

__global__ __launch_bounds__(256)
void scan1_kernel(const int* __restrict__ deg, int* __restrict__ bsum) {
  __shared__ int s[256];
  int gid = blockIdx.x * 256 + threadIdx.x;
  s[threadIdx.x] = (gid < NN) ? deg[gid] : 0;
  __syncthreads();
  for (int d = 128; d > 0; d >>= 1) {
    if (threadIdx.x < d) s[threadIdx.x] += s[threadIdx.x + d];
    __syncthreads();
  }
  if (threadIdx.x == 0) bsum[blockIdx.x] = s[0];
}

__global__ __launch_bounds__(256)
void scan2_kernel(const int* __restrict__ bsum, int* __restrict__ boff) {
  __shared__ int s[256];
  int t = threadIdx.x;
  int v = (t < 196) ? bsum[t] : 0;
  s[t] = v;
  __syncthreads();
  for (int d = 1; d < 256; d <<= 1) {
    int x = (t >= d) ? s[t - d] : 0;
    __syncthreads();
    s[t] += x;
    __syncthreads();
  }
  boff[t] = s[t] - v;   // exclusive
}

__global__ __launch_bounds__(256)
void scan3_kernel(const int* __restrict__ deg, const int* __restrict__ boff,
                  int* __restrict__ pos, int* __restrict__ cur) {
  __shared__ int s[256];
  int t = threadIdx.x, gid = blockIdx.x * 256 + t;
  int v = (gid < NN) ? deg[gid] : 0;
  s[t] = v;
  __syncthreads();
  for (int d = 1; d < 256; d <<= 1) {
    int x = (t >= d) ? s[t - d] : 0;
    __syncthreads();
    s[t] += x;
    __syncthreads();
  }
  int ex = s[t] - v + boff[blockIdx.x];
  if (gid < NN) {
    pos[gid] = ex;
    cur[gid] = ex;
    if (gid == NN - 1) pos[NN] = ex + v;
  }
}

// ---------------------------------------------------------------------------
// fused_tp: per 64-edge tile (natural edge order, all inputs streaming):
//   slot[e] = cur[rcv[e]]++  (CSR slot; random L2 atomics, hidden in staging)
//   h1 = swish(r@W1) (VALU) -> h2 = swish(h1@W2) (MFMA, s_hp permuted layout
//   pos(ch)=16*((ch>>1)&3)+2*(ch>>3)+(ch&1)) -> msg = (A'@W3re)*x_s (MFMA,
//   packed-f16 A' build) -> LDS bounce -> coalesced 128B row to msg[slot].
// Receiver-sorted msg rows => gather side reads sequentially. No eidx array.
// ---------------------------------------------------------------------------
__global__ __launch_bounds__(256, 4)
void fused_tp_kernel(const float* __restrict__ rad, const float* __restrict__ ef,
                     const _Float16* __restrict__ xup, const int* __restrict__ snd,
                     const int* __restrict__ rcv, const int* __restrict__ msk,
                     const float* __restrict__ W1,
                     const _Float16* __restrict__ w2p, const _Float16* __restrict__ w3p,
                     int* __restrict__ cur, _Float16* __restrict__ msg) {
  __shared__ float    s_r[64][9];
  __shared__ float    s_ef[64][4];
  __shared__ _Float16 s_xs[64][72];
  __shared__ _Float16 s_h1[64][72];
  __shared__ _Float16 s_hp[64][72];
  __shared__ int      s_slot[64];

  const int t = threadIdx.x;
  const long e0 = (long)blockIdx.x * 64;
  const int w = t >> 6, lane = t & 63, m = lane & 15, g = lane >> 4;

  // ---- stage: rad/ef sequential, CSR slot atomics, x_s gather ----
  for (int i = t; i < 512; i += 256) s_r[i >> 3][i & 7] = rad[e0 * 8 + i];
  s_ef[t >> 2][t & 3] = ef[e0 * 4 + t];
  if (t < 64) s_slot[t] = atomicAdd(&cur[rcv[e0 + t]], 1);
  {
    const int e = t >> 2, q = t & 3;
    const int sn = snd[e0 + e];
    const int mk = msk[e0 + e];
    uint4 v0 = {0, 0, 0, 0}, v1 = {0, 0, 0, 0};
    if (mk) {
      const uint4* src = reinterpret_cast<const uint4*>(xup + (long)sn * 64 + q * 16);
      v0 = src[0]; v1 = src[1];
    }
    *reinterpret_cast<uint4*>(&s_xs[e][q * 16]) = v0;
    *reinterpret_cast<uint4*>(&s_xs[e][q * 16 + 8]) = v1;
  }
  __syncthreads();

  // ---- h1 = swish(r @ W1): thread (e, 16 channels), W1 wave-uniform ----
  {
    const int e = t & 63, c0 = (t >> 6) * 16;
    float rv[8];
#pragma unroll
    for (int k = 0; k < 8; ++k) rv[k] = s_r[e][k];
#pragma unroll
    for (int p = 0; p < 8; ++p) {
      float a0 = 0.f, a1 = 0.f;
#pragma unroll
      for (int k = 0; k < 8; ++k) {
        a0 = fmaf(rv[k], W1[k * 64 + c0 + 2 * p], a0);
        a1 = fmaf(rv[k], W1[k * 64 + c0 + 2 * p + 1], a1);
      }
      half2v h = { (_Float16)swishf(a0), (_Float16)swishf(a1) };
      *reinterpret_cast<half2v*>(&s_h1[e][c0 + 2 * p]) = h;
    }
  }
  __syncthreads();

  // ---- h2 = swish(h1 @ W2) via MFMA -> s_hp (permuted channel layout).
  //      Wave w touches only rows [16w,16w+16) from here on: no barrier
  //      needed between h2 epilogue and the TP stage below. ----
  {
    f32x4 acc[4];
#pragma unroll
    for (int nt = 0; nt < 4; ++nt) acc[nt] = (f32x4){0.f, 0.f, 0.f, 0.f};
#pragma unroll
    for (int kk = 0; kk < 2; ++kk) {
      half8 a = *reinterpret_cast<const half8*>(&s_h1[w * 16 + m][32 * kk + 8 * g]);
#pragma unroll
      for (int nt = 0; nt < 4; ++nt) {
        half8 bfr = *reinterpret_cast<const half8*>(w2p + ((size_t)(kk * 4 + nt) * 64 + lane) * 8);
        acc[nt] = __builtin_amdgcn_mfma_f32_16x16x32_f16(a, bfr, acc[nt], 0, 0, 0);
      }
    }
    const int col = lane & 15, rg = lane >> 4;
    const int pbase = 16 * ((col >> 1) & 3) + 2 * (col >> 3) + (col & 1);
#pragma unroll
    for (int nt = 0; nt < 4; ++nt) {
      const int pos = pbase + 4 * nt;
#pragma unroll
      for (int i = 0; i < 4; ++i) {
        const int erow = w * 16 + rg * 4 + i;
        s_hp[erow][pos] = (_Float16)swishf(acc[nt][i]);
      }
    }
  }

  // ---- TP: msg = (A' @ W3re) * x_s  (packed-f16 A' build) ----
  {
    const int e_m = w * 16 + m;
    const _Float16* hrow = &s_hp[e_m][g * 16];
    half8 hlo = *reinterpret_cast<const half8*>(hrow);
    half8 hhi = *reinterpret_cast<const half8*>(hrow + 8);

    _Float16 efh[4];
#pragma unroll
    for (int l = 0; l < 4; ++l) efh[l] = (_Float16)s_ef[e_m][l];

    f32x4 acc[4];
#pragma unroll
    for (int nt = 0; nt < 4; ++nt) acc[nt] = (f32x4){0.f, 0.f, 0.f, 0.f};

#pragma unroll
    for (int ks = 0; ks < 8; ++ks) {
      const _Float16 h0  = (ks < 4) ? hlo[2 * ks]     : hhi[2 * (ks - 4)];
      const _Float16 h1v = (ks < 4) ? hlo[2 * ks + 1] : hhi[2 * (ks - 4) + 1];
      half8 a;
#pragma unroll
      for (int l = 0; l < 4; ++l) {
        a[l]     = h0  * efh[l];
        a[4 + l] = h1v * efh[l];
      }
#pragma unroll
      for (int nt = 0; nt < 4; ++nt) {
        half8 bfr = *reinterpret_cast<const half8*>(w3p + ((size_t)(ks * 4 + nt) * 64 + lane) * 8);
        acc[nt] = __builtin_amdgcn_mfma_f32_16x16x32_f16(a, bfr, acc[nt], 0, 0, 0);
      }
    }

    // multiply by x_s, pack f16 back into own s_hp rows (LDS bounce)
    const int col = lane & 15, rg = lane >> 4;
#pragma unroll
    for (int nt = 0; nt < 4; ++nt) {
      const int f = nt * 16 + col;
#pragma unroll
      for (int i = 0; i < 4; ++i) {
        const int e_row = w * 16 + rg * 4 + i;
        s_hp[e_row][f] = (_Float16)(acc[nt][i] * (float)s_xs[e_row][f]);
      }
    }
  }
  __syncthreads();

  // ---- coalesced 128B row store to CSR slot ----
  {
    const int e = t >> 2, q = t & 3;
    uint4 v0 = *reinterpret_cast<const uint4*>(&s_hp[e][q * 16]);
    uint4 v1 = *reinterpret_cast<const uint4*>(&s_hp[e][q * 16 + 8]);
    _Float16* dst = msg + (long)s_slot[e] * 64 + q * 16;
    *reinterpret_cast<uint4*>(dst) = v0;
    *reinterpret_cast<uint4*>(dst + 8) = v1;
  }
}

// ---------------------------------------------------------------------------
// gather_down: block owns 16 nodes; msg rows for node n are CONTIGUOUS slots
// [pos[n], pos[n+1]) -> purely sequential reads. Fused /16 @ W_down -> out.
// ---------------------------------------------------------------------------
__global__ __launch_bounds__(256, 8)
void gather_down_kernel(const _Float16* __restrict__ msg, const int* __restrict__ pos,
                        const float* __restrict__ W_dn, float* __restrict__ out) {
  __shared__ int   s_pos[17];
  __shared__ float s_agg[16][65];

  const int t = threadIdx.x;
  const int node0 = blockIdx.x * 16;

  if (t < 17) s_pos[t] = pos[node0 + t];
  __syncthreads();

  const int tg = t >> 4, tl = t & 15;
  float a0 = 0.f, a1 = 0.f, a2 = 0.f, a3 = 0.f;
  for (int a = s_pos[tg]; a < s_pos[tg + 1]; ++a) {
    half4v v = *reinterpret_cast<const half4v*>(msg + (long)a * 64 + tl * 4);
    a0 += (float)v[0]; a1 += (float)v[1]; a2 += (float)v[2]; a3 += (float)v[3];
  }
  s_agg[tg][tl * 4 + 0] = a0;
  s_agg[tg][tl * 4 + 1] = a1;
  s_agg[tg][tl * 4 + 2] = a2;
  s_agg[tg][tl * 4 + 3] = a3;
  __syncthreads();

  // fused linear_down: out[node0+r] = (s_agg[r]/16) @ W_dn
  {
    const int r = t >> 4, c0 = (t & 15) * 4;
    float b0 = 0.f, b1 = 0.f, b2 = 0.f, b3 = 0.f;
    for (int k = 0; k < 64; ++k) {
      const float x = s_agg[r][k];
      const float4 wv = *reinterpret_cast<const float4*>(W_dn + k * 64 + c0);
      b0 = fmaf(x, wv.x, b0);
      b1 = fmaf(x, wv.y, b1);
      b2 = fmaf(x, wv.z, b2);
      b3 = fmaf(x, wv.w, b3);
    }
    float4 o = { b0 * 0.0625f, b1 * 0.0625f, b2 * 0.0625f, b3 * 0.0625f };
    *reinterpret_cast<float4*>(out + (long)(node0 + r) * 64 + c0) = o;
  }
}

extern "C" void kernel_launch(void* const* d_in, const int* in_sizes, int n_in,
                              void* d_out, int out_size, void* d_ws, size_t ws_size,
                              hipStream_t stream) {
  const float* nf   = (const float*)d_in[0];
  const float* ef   = (const float*)d_in[1];
  const float* rad  = (const float*)d_in[2];
  const int*   snd  = (const int*)d_in[3];
  const int*   rcv  = (const int*)d_in[4];
  const int*   msk  = (const int*)d_in[5];
  const float* W_up = (const float*)d_in[6];
  const float* W1   = (const float*)d_in[7];
  const float* W2   = (const float*)d_in[8];
  const float* W3   = (const float*)d_in[9];
  const float* W_dn = (const float*)d_in[10];
  float* out = (float*)d_out;

  // workspace layout (~109.5 MB)
  _Float16* msg  = (_Float16*)d_ws;                 // 800000*64 f16 = 102.4 MB
  _Float16* xbuf = msg + (size_t)NE * 64;           // 6.4 MB
  _Float16* w3p  = xbuf + (size_t)NN * 64;          // 32 KB
  _Float16* w2p  = w3p + 2048 * 8;                  // 8 KB
  int*      deg  = (int*)(w2p + 512 * 8);           // 200 KB
  int*      pos  = deg + NN;                        // 200 KB (+1)
  int*      cur  = pos + NN + 1;                    // 200 KB
  int*      bsum = cur + NN;                        // 1 KB
  int*      boff = bsum + 256;                      // 1 KB

  hipMemsetAsync(deg, 0, (size_t)NN * sizeof(int), stream);

  hist_kernel<<<NE / 256, 256, 0, stream>>>(rcv, deg);
  scan1_kernel<<<196, 256, 0, stream>>>(deg, bsum);
  scan2_kernel<<<1, 256, 0, stream>>>(bsum, boff);
  scan3_kernel<<<196, 256, 0, stream>>>(deg, boff, pos, cur);

  pack_kernel<<<10, 256, 0, stream>>>(W3, W2, w3p, w2p);
  linear_up_kernel<<<(NN * 64) / 256, 256, 0, stream>>>(nf, W_up, xbuf);

  fused_tp_kernel<<<NE / 64, 256, 0, stream>>>(rad, ef, xbuf, snd, rcv, msk,
                                               W1, w2p, w3p, cur, msg);

  gather_down_kernel<<<NN / 16, 256, 0, stream>>>(msg, pos, W_dn, out);
}

// Round 10
// 266.160 us; speedup vs baseline: 2.9782x; 1.0763x over previous
//
#include <hip/hip_runtime.h>
#include <hip/hip_bf16.h>

typedef _Float16 half8 __attribute__((ext_vector_type(8)));
typedef _Float16 half4v __attribute__((ext_vector_type(4)));
typedef _Float16 half2v __attribute__((ext_vector_type(2)));
typedef float f32x4 __attribute__((ext_vector_type(4)));

#define NN 50000
#define NE 800000

// fast swish: v * rcp(1+exp(-v))
__device__ __forceinline__ float swishf(float v) {
  return v * __builtin_amdgcn_rcpf(1.f + __expf(-v));
}

// ---------------------------------------------------------------------------
// Pack W3 [64][256] and W2 [64][64] into MFMA-B fragment order (f16).
// w3p[t*8+u] = W3[j>>2][4*f+(j&3)],  j=32ks+8(lane>>4)+u, f=16nt+(lane&15)
// w2p[t*8+u] = W2[32kk+8(lane>>4)+u][16nt+(lane&15)]
// ---------------------------------------------------------------------------
__global__ void pack_kernel(const float* __restrict__ W3, const float* __restrict__ W2,
                            _Float16* __restrict__ w3p, _Float16* __restrict__ w2p) {
  const int b = blockIdx.x, tid = threadIdx.x;
  if (b < 8) {
    int t = b * 256 + tid;
    int lane = t & 63, nt = (t >> 6) & 3, ks = t >> 8;
    int f = 16 * nt + (lane & 15);
    int jb = 32 * ks + 8 * (lane >> 4);
#pragma unroll
    for (int u = 0; u < 8; ++u) {
      int j = jb + u;
      w3p[t * 8 + u] = (_Float16)W3[(j >> 2) * 256 + 4 * f + (j & 3)];
    }
  } else {
    int t = (b - 8) * 256 + tid;
    if (t < 512) {
      int lane = t & 63, nt = (t >> 6) & 3, kk = t >> 8;
      int c = 16 * nt + (lane & 15);
      int kb = 32 * kk + 8 * (lane >> 4);
#pragma unroll
      for (int u = 0; u < 8; ++u)
        w2p[t * 8 + u] = (_Float16)W2[(kb + u) * 64 + c];
    }
  }
}

// ---------------------------------------------------------------------------
// linear_up: Y[row] = X[row] @ W  (f16 out)
// ---------------------------------------------------------------------------
__global__ __launch_bounds__(256)
void linear_up_kernel(const float* __restrict__ X, const float* __restrict__ W,
                      _Float16* __restrict__ Y) {
  int gid = blockIdx.x * 256 + (int)threadIdx.x;
  int row = gid >> 6;
  int lane = threadIdx.x & 63;
  const float* xr = X + (long)row * 64;
  float acc = 0.f;
#pragma unroll
  for (int k = 0; k < 64; ++k) acc = fmaf(xr[k], W[k * 64 + lane], acc);
  Y[(long)row * 64 + lane] = (_Float16)acc;
}

// ---------------------------------------------------------------------------
// CSR offsets: hist, 3-phase coalesced scan (pos = exclusive prefix; cur copy)
// ---------------------------------------------------------------------------
__global__ void hist_kernel(const int* __restrict__ rcv, int* __restrict__ deg) {
  int e = blockIdx.x * 256 + threadIdx.x;
  if (e < NE) atomicAdd(&deg[rcv[e]], 1);
}

__global__ __launch_bounds__(256)
void scan1_kernel(const int* __restrict__ deg, int* __restrict__ bsum) {
  __shared__ int s[256];
  int gid = blockIdx.x * 256 + threadIdx.x;
  s[threadIdx.x] = (gid < NN) ? deg[gid] : 0;
  __syncthreads();
  for (int d = 128; d > 0; d >>= 1) {
    if (threadIdx.x < d) s[threadIdx.x] += s[threadIdx.x + d];
    __syncthreads();
  }
  if (threadIdx.x == 0) bsum[blockIdx.x] = s[0];
}

__global__ __launch_bounds__(256)
void scan2_kernel(const int* __restrict__ bsum, int* __restrict__ boff) {
  __shared__ int s[256];
  int t = threadIdx.x;
  int v = (t < 196) ? bsum[t] : 0;
  s[t] = v;
  __syncthreads();
  for (int d = 1; d < 256; d <<= 1) {
    int x = (t >= d) ? s[t - d] : 0;
    __syncthreads();
    s[t] += x;
    __syncthreads();
  }
  boff[t] = s[t] - v;   // exclusive
}

__global__ __launch_bounds__(256)
void scan3_kernel(const int* __restrict__ deg, const int* __restrict__ boff,
                  int* __restrict__ pos, int* __restrict__ cur) {
  __shared__ int s[256];
  int t = threadIdx.x, gid = blockIdx.x * 256 + t;
  int v = (gid < NN) ? deg[gid] : 0;
  s[t] = v;
  __syncthreads();
  for (int d = 1; d < 256; d <<= 1) {
    int x = (t >= d) ? s[t - d] : 0;
    __syncthreads();
    s[t] += x;
    __syncthreads();
  }
  int ex = s[t] - v + boff[blockIdx.x];
  if (gid < NN) {
    pos[gid] = ex;
    cur[gid] = ex;
    if (gid == NN - 1) pos[NN] = ex + v;
  }
}

// ---------------------------------------------------------------------------
// fused_tp v2: ONE barrier per tile; everything after stage is wave-private.
//   stage (rad/ef/x_s/slot) -> barrier ->
//   h1 in REGISTERS, lane (m,g) computes exactly its A-frag channels
//   {32kk+8g+u} of row 16w+m (f32 FMA, W1 float4 from L1) ->
//   h2 = swish(h1@W2) MFMA -> s_hp own-wave slab (permuted ch layout) ->
//   TP msg=(A'@W3re)*x_s MFMA -> s_hp bounce -> coalesced row to msg[slot].
// ---------------------------------------------------------------------------
__global__ __launch_bounds__(256, 6)
void fused_tp_kernel(const float* __restrict__ rad, const float* __restrict__ ef,
                     const _Float16* __restrict__ xup, const int* __restrict__ snd,
                     const int* __restrict__ rcv, const int* __restrict__ msk,
                     const float* __restrict__ W1,
                     const _Float16* __restrict__ w2p, const _Float16* __restrict__ w3p,
                     int* __restrict__ cur, _Float16* __restrict__ msg) {
  __shared__ float    s_r[64][9];
  __shared__ float    s_ef[64][4];
  __shared__ _Float16 s_xs[64][72];
  __shared__ _Float16 s_hp[64][72];
  __shared__ int      s_slot[64];

  const int t = threadIdx.x;
  const long e0 = (long)blockIdx.x * 64;
  const int w = t >> 6, lane = t & 63, m = lane & 15, g = lane >> 4;

  // ---- stage: rad/ef sequential, CSR slot atomics, x_s gather ----
  for (int i = t; i < 512; i += 256) s_r[i >> 3][i & 7] = rad[e0 * 8 + i];
  s_ef[t >> 2][t & 3] = ef[e0 * 4 + t];
  if (t < 64) s_slot[t] = atomicAdd(&cur[rcv[e0 + t]], 1);
  {
    const int e = t >> 2, q = t & 3;
    const int sn = snd[e0 + e];
    const int mk = msk[e0 + e];
    uint4 v0 = {0, 0, 0, 0}, v1 = {0, 0, 0, 0};
    if (mk) {
      const uint4* src = reinterpret_cast<const uint4*>(xup + (long)sn * 64 + q * 16);
      v0 = src[0]; v1 = src[1];
    }
    *reinterpret_cast<uint4*>(&s_xs[e][q * 16]) = v0;
    *reinterpret_cast<uint4*>(&s_xs[e][q * 16 + 8]) = v1;
  }
  __syncthreads();   // the ONLY barrier

  const int e_m = w * 16 + m;

  // ---- h1 in registers: lane computes its own A-frag channels ----
  float rv[8];
#pragma unroll
  for (int k = 0; k < 8; ++k) rv[k] = s_r[e_m][k];

  half8 afrag[2];
#pragma unroll
  for (int kk = 0; kk < 2; ++kk) {
    float acc[8];
#pragma unroll
    for (int u = 0; u < 8; ++u) acc[u] = 0.f;
#pragma unroll
    for (int k = 0; k < 8; ++k) {
      const float4 wa = *reinterpret_cast<const float4*>(W1 + k * 64 + 32 * kk + 8 * g);
      const float4 wb = *reinterpret_cast<const float4*>(W1 + k * 64 + 32 * kk + 8 * g + 4);
      acc[0] = fmaf(rv[k], wa.x, acc[0]);
      acc[1] = fmaf(rv[k], wa.y, acc[1]);
      acc[2] = fmaf(rv[k], wa.z, acc[2]);
      acc[3] = fmaf(rv[k], wa.w, acc[3]);
      acc[4] = fmaf(rv[k], wb.x, acc[4]);
      acc[5] = fmaf(rv[k], wb.y, acc[5]);
      acc[6] = fmaf(rv[k], wb.z, acc[6]);
      acc[7] = fmaf(rv[k], wb.w, acc[7]);
    }
#pragma unroll
    for (int u = 0; u < 8; ++u) afrag[kk][u] = (_Float16)swishf(acc[u]);
  }

  // ---- h2 = swish(h1 @ W2) via MFMA -> s_hp own-wave slab (permuted) ----
  {
    f32x4 acc2[4];
#pragma unroll
    for (int nt = 0; nt < 4; ++nt) acc2[nt] = (f32x4){0.f, 0.f, 0.f, 0.f};
#pragma unroll
    for (int kk = 0; kk < 2; ++kk) {
#pragma unroll
      for (int nt = 0; nt < 4; ++nt) {
        half8 bfr = *reinterpret_cast<const half8*>(w2p + ((size_t)(kk * 4 + nt) * 64 + lane) * 8);
        acc2[nt] = __builtin_amdgcn_mfma_f32_16x16x32_f16(afrag[kk], bfr, acc2[nt], 0, 0, 0);
      }
    }
    const int col = lane & 15, rg = lane >> 4;
    const int pbase = 16 * ((col >> 1) & 3) + 2 * (col >> 3) + (col & 1);
#pragma unroll
    for (int nt = 0; nt < 4; ++nt) {
      const int pos = pbase + 4 * nt;
#pragma unroll
      for (int i = 0; i < 4; ++i) {
        const int erow = w * 16 + rg * 4 + i;   // own-wave slab
        s_hp[erow][pos] = (_Float16)swishf(acc2[nt][i]);
      }
    }
  }

  // ---- TP: msg = (A' @ W3re) * x_s  (reads s_hp own-wave slab) ----
  {
    const _Float16* hrow = &s_hp[e_m][g * 16];
    half8 hlo = *reinterpret_cast<const half8*>(hrow);
    half8 hhi = *reinterpret_cast<const half8*>(hrow + 8);

    _Float16 efh[4];
#pragma unroll
    for (int l = 0; l < 4; ++l) efh[l] = (_Float16)s_ef[e_m][l];

    f32x4 acc[4];
#pragma unroll
    for (int nt = 0; nt < 4; ++nt) acc[nt] = (f32x4){0.f, 0.f, 0.f, 0.f};

#pragma unroll
    for (int ks = 0; ks < 8; ++ks) {
      const _Float16 h0  = (ks < 4) ? hlo[2 * ks]     : hhi[2 * (ks - 4)];
      const _Float16 h1v = (ks < 4) ? hlo[2 * ks + 1] : hhi[2 * (ks - 4) + 1];
      half8 a;
#pragma unroll
      for (int l = 0; l < 4; ++l) {
        a[l]     = h0  * efh[l];
        a[4 + l] = h1v * efh[l];
      }
#pragma unroll
      for (int nt = 0; nt < 4; ++nt) {
        half8 bfr = *reinterpret_cast<const half8*>(w3p + ((size_t)(ks * 4 + nt) * 64 + lane) * 8);
        acc[nt] = __builtin_amdgcn_mfma_f32_16x16x32_f16(a, bfr, acc[nt], 0, 0, 0);
      }
    }

    // multiply by x_s, pack f16 into own-wave s_hp rows (LDS bounce)
    const int col = lane & 15, rg = lane >> 4;
#pragma unroll
    for (int nt = 0; nt < 4; ++nt) {
      const int f = nt * 16 + col;
#pragma unroll
      for (int i = 0; i < 4; ++i) {
        const int e_row = w * 16 + rg * 4 + i;
        s_hp[e_row][f] = (_Float16)(acc[nt][i] * (float)s_xs[e_row][f]);
      }
    }
  }

  // ---- coalesced 128B row store to CSR slot (own-wave rows: e=t>>2) ----
  {
    const int e = t >> 2, q = t & 3;
    uint4 v0 = *reinterpret_cast<const uint4*>(&s_hp[e][q * 16]);
    uint4 v1 = *reinterpret_cast<const uint4*>(&s_hp[e][q * 16 + 8]);
    _Float16* dst = msg + (long)s_slot[e] * 64 + q * 16;
    *reinterpret_cast<uint4*>(dst) = v0;
    *reinterpret_cast<uint4*>(dst + 8) = v1;
  }
}

// ---------------------------------------------------------------------------
// gather_down: block owns 16 nodes; msg rows for node n are CONTIGUOUS slots
// [pos[n], pos[n+1]) -> purely sequential reads. Fused /16 @ W_down -> out.
// ---------------------------------------------------------------------------
__global__ __launch_bounds__(256, 8)
void gather_down_kernel(const _Float16* __restrict__ msg, const int* __restrict__ pos,
                        const float* __restrict__ W_dn, float* __restrict__ out) {
  __shared__ int   s_pos[17];
  __shared__ float s_agg[16][65];

  const int t = threadIdx.x;
  const int node0 = blockIdx.x * 16;

  if (t < 17) s_pos[t] = pos[node0 + t];
  __syncthreads();

  const int tg = t >> 4, tl = t & 15;
  float a0 = 0.f, a1 = 0.f, a2 = 0.f, a3 = 0.f;
  for (int a = s_pos[tg]; a < s_pos[tg + 1]; ++a) {
    half4v v = *reinterpret_cast<const half4v*>(msg + (long)a * 64 + tl * 4);
    a0 += (float)v[0]; a1 += (float)v[1]; a2 += (float)v[2]; a3 += (float)v[3];
  }
  s_agg[tg][tl * 4 + 0] = a0;
  s_agg[tg][tl * 4 + 1] = a1;
  s_agg[tg][tl * 4 + 2] = a2;
  s_agg[tg][tl * 4 + 3] = a3;
  __syncthreads();

  // fused linear_down: out[node0+r] = (s_agg[r]/16) @ W_dn
  {
    const int r = t >> 4, c0 = (t & 15) * 4;
    float b0 = 0.f, b1 = 0.f, b2 = 0.f, b3 = 0.f;
    for (int k = 0; k < 64; ++k) {
      const float x = s_agg[r][k];
      const float4 wv = *reinterpret_cast<const float4*>(W_dn + k * 64 + c0);
      b0 = fmaf(x, wv.x, b0);
      b1 = fmaf(x, wv.y, b1);
      b2 = fmaf(x, wv.z, b2);
      b3 = fmaf(x, wv.w, b3);
    }
    float4 o = { b0 * 0.0625f, b1 * 0.0625f, b2 * 0.0625f, b3 * 0.0625f };
    *reinterpret_cast<float4*>(out + (long)(node0 + r) * 64 + c0) = o;
  }
}

extern "C" void kernel_launch(void* const* d_in, const int* in_sizes, int n_in,
                              void* d_out, int out_size, void* d_ws, size_t ws_size,
                              hipStream_t stream) {
  const float* nf   = (const float*)d_in[0];
  const float* ef   = (const float*)d_in[1];
  const float* rad  = (const float*)d_in[2];
  const int*   snd  = (const int*)d_in[3];
  const int*   rcv  = (const int*)d_in[4];
  const int*   msk  = (const int*)d_in[5];
  const float* W_up = (const float*)d_in[6];
  const float* W1   = (const float*)d_in[7];
  const float* W2   = (const float*)d_in[8];
  const float* W3   = (const float*)d_in[9];
  const float* W_dn = (const float*)d_in[10];
  float* out = (float*)d_out;

  // workspace layout (~109.5 MB)
  _Float16* msg  = (_Float16*)d_ws;                 // 800000*64 f16 = 102.4 MB
  _Float16* xbuf = msg + (size_t)NE * 64;           // 6.4 MB
  _Float16* w3p  = xbuf + (size_t)NN * 64;          // 32 KB
  _Float16* w2p  = w3p + 2048 * 8;                  // 8 KB
  int*      deg  = (int*)(w2p + 512 * 8);           // 200 KB
  int*      pos  = deg + NN;                        // 200 KB (+1)
  int*      cur  = pos + NN + 1;                    // 200 KB
  int*      bsum = cur + NN;                        // 1 KB
  int*      boff = bsum + 256;                      // 1 KB

  hipMemsetAsync(deg, 0, (size_t)NN * sizeof(int), stream);

  hist_kernel<<<NE / 256, 256, 0, stream>>>(rcv, deg);
  scan1_kernel<<<196, 256, 0, stream>>>(deg, bsum);
  scan2_kernel<<<1, 256, 0, stream>>>(bsum, boff);
  scan3_kernel<<<196, 256, 0, stream>>>(deg, boff, pos, cur);

  pack_kernel<<<10, 256, 0, stream>>>(W3, W2, w3p, w2p);
  linear_up_kernel<<<(NN * 64) / 256, 256, 0, stream>>>(nf, W_up, xbuf);

  fused_tp_kernel<<<NE / 64, 256, 0, stream>>>(rad, ef, xbuf, snd, rcv, msk,
                                               W1, w2p, w3p, cur, msg);

  gather_down_kernel<<<NN / 16, 256, 0, stream>>>(msg, pos, W_dn, out);
}